// Round 8
// baseline (126.878 us; speedup 1.0000x reference)
//
#include <hip/hip_runtime.h>
#include <hip/hip_bf16.h>

// B=16, T=12, N=1024, F_IN=F_OUT=64, K=3
#define BB 16
#define TT 12
#define NN 1024
#define FF 64
#define KC 3

typedef __bf16  bf16x8 __attribute__((ext_vector_type(8)));
typedef float   f32x4  __attribute__((ext_vector_type(4)));
typedef float   f32x16 __attribute__((ext_vector_type(16)));
typedef unsigned short u16;

#define A_TILE  24576      // fallback kernel tile (128B rows, XOR swizzle)
#define A_ROW   144        // main kernel: padded row bytes (64 bf16 + 16B pad)
#define A_TILEP (KC * 64 * A_ROW)   // 27648
#define MFMA_B(a, b, c) __builtin_amdgcn_mfma_f32_32x32x16_bf16(a, b, c, 0, 0, 0)

// workspace: y_frags [192 bt][16 jt][512 chunk][8 e] bf16 = 25165824 B
//            cheb_bf [3][1024][1024] bf16 = 6291456 B
#define YF_BYTES 25165824ull
#define CB_BYTES 6291456ull

static __device__ __forceinline__ u16 f2bf(float v) {
    union { __bf16 b; u16 u; } c; c.b = (__bf16)v; return c.u;
}

// ---------------- prepass 1: x [B,T,N,F] f32 -> y_frags bf16 (proven) -------
__global__ __launch_bounds__(256) void x_to_yfrags(
    const float* __restrict__ x, u16* __restrict__ y)
{
    __shared__ char tl[64 * 128];
    const int tid = threadIdx.x;
    const int bt  = blockIdx.x >> 4;
    const int jt  = blockIdx.x & 15;
    const int f   = tid & 63;
    const int jr  = tid >> 6;

    const float* xp = x + ((size_t)bt * NN + jt * 64 + jr) * FF + f;
    #pragma unroll
    for (int stp = 0; stp < 16; ++stp) {
        int j = stp * 4 + jr;
        u16 h = f2bf(xp[stp * 4 * FF]);
        *reinterpret_cast<u16*>(tl + j * 128 + ((f * 2) ^ ((j & 7) << 4))) = h;
    }
    __syncthreads();

    u16* yo = y + ((size_t)bt * 16 + jt) * 4096;
    #pragma unroll
    for (int p = 0; p < 2; ++p) {
        int c  = tid + p * 256;
        int s  = c >> 6, fo = c & 63;
        int j0 = (s >> 1) * 16 + (s & 1) * 8;
        u16 h[8];
        #pragma unroll
        for (int e = 0; e < 8; ++e)
            h[e] = *reinterpret_cast<u16*>(tl + (j0 + e) * 128 + ((fo * 2) ^ (e << 4)));
        uint4 w;
        w.x = h[0] | ((unsigned)h[1] << 16);
        w.y = h[2] | ((unsigned)h[3] << 16);
        w.z = h[4] | ((unsigned)h[5] << 16);
        w.w = h[6] | ((unsigned)h[7] << 16);
        *reinterpret_cast<uint4*>(yo + (size_t)c * 8) = w;
    }
}

// ---------------- prepass 2: cheb f32 -> bf16 flat copy (proven) ------------
__global__ __launch_bounds__(256) void cheb_to_bf16(
    const float* __restrict__ c, u16* __restrict__ o)
{
    const size_t i = ((size_t)blockIdx.x * 256 + threadIdx.x) * 8;
    f32x4 a = *reinterpret_cast<const f32x4*>(c + i);
    f32x4 b = *reinterpret_cast<const f32x4*>(c + i + 4);
    u16 h[8];
    #pragma unroll
    for (int e = 0; e < 4; ++e) { h[e] = f2bf(a[e]); h[e + 4] = f2bf(b[e]); }
    uint4 w;
    w.x = h[0] | ((unsigned)h[1] << 16);
    w.y = h[2] | ((unsigned)h[3] << 16);
    w.z = h[4] | ((unsigned)h[5] << 16);
    w.w = h[6] | ((unsigned)h[7] << 16);
    *reinterpret_cast<uint4*>(o + i) = w;
}

// ---------------- main: 256 thr (4 waves), 1536 blocks, 2 indep blocks/CU ---
// block = (b, i-tile 64, t-pair); waves: wm = wid>>1 (t in pair), wn = wid&1
__global__ __launch_bounds__(256, 2) void cheb_main(
    const u16*  __restrict__ yfr,    // y_frags
    const float* __restrict__ att,   // [B,N,N] f32
    const u16*  __restrict__ chb,    // cheb bf16 [K,N,N]
    const float* __restrict__ Theta, // [K,F,F] f32
    float* __restrict__ out)         // [B,T,N,F] f32
{
    // A double buffer, padded rows (144B) -> bank-optimal reads AND writes
    __shared__ __align__(16) char lds[2 * A_TILEP];   // 55296 B
    char* Ab0 = lds;
    char* Ab1 = lds + A_TILEP;

    const int tid  = threadIdx.x;
    const int lane = tid & 63;
    const int wid  = tid >> 6;

    // XCD swizzle: 1536 % 8 == 0, chunk 192 (= 2 b's per XCD)
    const int wg = (blockIdx.x & 7) * 192 + (blockIdx.x >> 3);
    const int b  = wg / 96;
    const int rm = wg % 96;
    const int it = rm / 6;
    const int tc = rm % 6;
    const int i_base = it * 64;
    const int t_base = tc * 2;

    const int wm  = wid >> 1;   // 0..1 : t in pair
    const int wn  = wid & 1;    // 0..1 : i half
    const int l31 = lane & 31;
    const int lg  = lane >> 5;

    // A-staging map: r_a = tid>>2 (row 0..63), g_h = tid&3 (16-j group)
    const int r_a = tid >> 2;
    const int g_h = tid & 3;
    const float* attR = att + ((size_t)b * NN + i_base + r_a) * NN + g_h * 16;
    const u16*   chR  = chb + ((size_t)(i_base + r_a)) * NN + g_h * 16;

    // per-wave y-frag base (bt = b*12 + t_base + wm)
    const u16* yt0 = yfr + ((size_t)(b * TT + t_base + wm) * 16) * 4096
                   + (size_t)(lg * 512 + l31 * 8);

    f32x16 acc[KC][2] = {};
    const int arow = (wn * 32 + l31) * A_ROW;

    // staging registers
    f32x4 ra[4];            // att  (16 f32)
    bf16x8 rc[KC][2];       // cheb (16 bf16 per k)
    bf16x8 y0[8], y1[8];    // y-frag double reg-buffer (one full jt each)

    auto LOADS = [&](int j0) {
        #pragma unroll
        for (int q = 0; q < 4; ++q)
            ra[q] = *reinterpret_cast<const f32x4*>(attR + j0 + q * 4);
        #pragma unroll
        for (int k = 0; k < KC; ++k) {
            const u16* cp = chR + (size_t)k * NN * NN + j0;
            rc[k][0] = *reinterpret_cast<const bf16x8*>(cp);
            rc[k][1] = *reinterpret_cast<const bf16x8*>(cp + 8);
        }
    };
    auto FINISH = [&](char* Ab) {
        #pragma unroll
        for (int k = 0; k < KC; ++k) {
            #pragma unroll
            for (int h = 0; h < 2; ++h) {
                bf16x8 w;
                #pragma unroll
                for (int e = 0; e < 8; ++e) {
                    float av = ra[h * 2 + (e >> 2)][e & 3];
                    w[e] = (__bf16)(av * (float)rc[k][h][e]);
                }
                *reinterpret_cast<bf16x8*>(
                    Ab + (k * 64 + r_a) * A_ROW + g_h * 32 + h * 16) = w;
            }
        }
    };
    auto loadY = [&](bf16x8* yd, int jt) {
        const u16* yt = yt0 + (size_t)jt * 4096;
        #pragma unroll
        for (int q = 0; q < 4; ++q) {
            yd[q * 2]     = *reinterpret_cast<const bf16x8*>(yt + q * 1024);
            yd[q * 2 + 1] = *reinterpret_cast<const bf16x8*>(yt + q * 1024 + 256);
        }
    };

    auto phase4 = [&](const char* Abase, const bf16x8* yv) {
        #pragma unroll
        for (int kk = 0; kk < 4; ++kk) {
            const int off = (kk * 2 + lg) * 16;
            bf16x8 af0 = yv[kk * 2];
            bf16x8 af1 = yv[kk * 2 + 1];
            bf16x8 b0 = *reinterpret_cast<const bf16x8*>(Abase + arow + off);
            bf16x8 b1 = *reinterpret_cast<const bf16x8*>(Abase + 64 * A_ROW + arow + off);
            bf16x8 b2 = *reinterpret_cast<const bf16x8*>(Abase + 128 * A_ROW + arow + off);
            __builtin_amdgcn_s_setprio(1);
            acc[0][0] = MFMA_B(af0, b0, acc[0][0]); acc[0][1] = MFMA_B(af1, b0, acc[0][1]);
            acc[1][0] = MFMA_B(af0, b1, acc[1][0]); acc[1][1] = MFMA_B(af1, b1, acc[1][1]);
            acc[2][0] = MFMA_B(af0, b2, acc[2][0]); acc[2][1] = MFMA_B(af1, b2, acc[2][1]);
            __builtin_amdgcn_s_setprio(0);
        }
    };

    auto body = [&](char* cur, char* alt, bf16x8* yC, bf16x8* yN, int jt) {
        loadY(yN, (jt + 1) & 15);                 // y(jt+1) in flight
        phase4(cur, yC);                          // A[jt] x y(jt)
        if (jt < 15) {
            FINISH(alt);                          // stage A[jt+1] (waits att/cheb regs)
            LOADS(((jt + 2) & 15) * 64);          // issue att/cheb(jt+2)
        }
        asm volatile("s_waitcnt lgkmcnt(0)" ::: "memory");
        __builtin_amdgcn_s_barrier();             // globals stay in flight across
    };

    // prologue: stage A[0]; att/cheb(1) + y(0) in flight
    LOADS(0);
    loadY(y0, 0);
    FINISH(Ab0);
    LOADS(64);
    asm volatile("s_waitcnt lgkmcnt(0)" ::: "memory");
    __builtin_amdgcn_s_barrier();

    #pragma unroll 1
    for (int h = 0; h < 8; ++h) {
        body(Ab0, Ab1, y0, y1, 2 * h);
        body(Ab1, Ab0, y1, y0, 2 * h + 1);
    }

    // ---- stage Theta fragments (24 frags * 64 lanes * 16B = 24576 B) ----
    {
        const int fi0 = wid * 6;
        #pragma unroll
        for (int q = 0; q < 6; ++q) {
            int fi = fi0 + q;
            int k  = fi >> 3;
            int mo = (fi >> 2) & 1;
            int s  = fi & 3;
            int o  = 32 * mo + l31;
            int fb = 32 * (s >> 1) + 16 * (s & 1) + 4 * lg;
            bf16x8 v;
            #pragma unroll
            for (int e = 0; e < 8; ++e) {
                int f = fb + (e & 3) + 8 * (e >> 2);
                v[e] = (__bf16)Theta[(k * FF + f) * FF + o];
            }
            *reinterpret_cast<bf16x8*>(lds + (fi * 64 + lane) * 16) = v;
        }
    }
    __syncthreads();

    // ---- epilogue: out[i][o] = sum_{k,f} rhsT[f][i]^T * Theta ----
    f32x16 of[2] = {};
    #pragma unroll
    for (int k = 0; k < KC; ++k) {
        #pragma unroll
        for (int s = 0; s < 4; ++s) {
            bf16x8 pb;
            #pragma unroll
            for (int e = 0; e < 8; ++e)
                pb[e] = (__bf16)acc[k][s >> 1][e + 8 * (s & 1)];
            #pragma unroll
            for (int mo = 0; mo < 2; ++mo) {
                bf16x8 th = *reinterpret_cast<const bf16x8*>(
                    lds + ((((k * 2 + mo) * 4 + s) * 64) + lane) * 16);
                of[mo] = MFMA_B(pb, th, of[mo]);
            }
        }
    }

    const int t = t_base + wm;
    float* op = out + (((size_t)b * TT + t) * NN + i_base + wn * 32) * FF;
    #pragma unroll
    for (int mo = 0; mo < 2; ++mo) {
        #pragma unroll
        for (int r = 0; r < 16; ++r) {
            int row = (r & 3) + 8 * (r >> 2) + 4 * lg;
            int o   = 32 * mo + l31;
            float v = of[mo][r];
            op[(size_t)row * FF + o] = v > 0.0f ? v : 0.0f;
        }
    }
}

// ---------------- fallback (R3 kernel, used when ws too small) ----------------
__global__ __launch_bounds__(512, 2) void cheb_fused(
    const float* __restrict__ x, const float* __restrict__ att,
    const float* __restrict__ cheb, const float* __restrict__ Theta,
    float* __restrict__ out)
{
    __shared__ __align__(16) char lds_raw[2 * (A_TILE + 32768)];
    char* Ab0 = lds_raw;
    char* Xb0 = lds_raw + A_TILE;
    char* Ab1 = lds_raw + A_TILE + 32768;
    char* Xb1 = Ab1 + A_TILE;

    const int tid  = threadIdx.x;
    const int lane = tid & 63;
    const int wid  = tid >> 6;
    const int wg = (blockIdx.x & 7) * 96 + (blockIdx.x >> 3);
    const int b  = wg / 48;
    const int it = (wg % 48) / 3;
    const int tc = wg % 3;
    const int i_base = it * 64;
    const int t_base = tc * 4;
    const int wm  = wid >> 1;
    const int wn  = wid & 1;
    const int l31 = lane & 31;
    const int lg  = lane >> 5;
    const int sw3 = (l31 >> 2) & 7;
    const float* attB = att + (size_t)b * NN * NN;
    const float* xB   = x + (size_t)b * TT * NN * FF;
    const int r_a = tid >> 3;
    const int g_a = tid & 7;
    const int swza_st = ((r_a >> 2) & 7) << 4;
    int tl_s[4], jj_s[4], f_s[4], swzx_st[4];
    #pragma unroll
    for (int s = 0; s < 4; ++s) {
        int u = tid + s * 512;
        tl_s[s] = u >> 9;
        int rem = u & 511;
        jj_s[s] = (rem >> 4) * 2;
        f_s[s]  = (rem & 15) * 4;
        swzx_st[s] = ((f_s[s] >> 2) & 7) << 4;
    }
    f32x4 ra0, ra1, rc0[KC], rc1[KC], rx0[4], rx1[4];
    auto load_tile = [&](int j0) {
        const float* ap = attB + (size_t)(i_base + r_a) * NN + j0 + g_a * 8;
        ra0 = *reinterpret_cast<const f32x4*>(ap);
        ra1 = *reinterpret_cast<const f32x4*>(ap + 4);
        #pragma unroll
        for (int k = 0; k < KC; ++k) {
            const float* cp = cheb + ((size_t)k * NN + i_base + r_a) * NN + j0 + g_a * 8;
            rc0[k] = *reinterpret_cast<const f32x4*>(cp);
            rc1[k] = *reinterpret_cast<const f32x4*>(cp + 4);
        }
        #pragma unroll
        for (int s = 0; s < 4; ++s) {
            const float* xp = xB + ((size_t)(t_base + tl_s[s]) * NN + j0 + jj_s[s]) * FF + f_s[s];
            rx0[s] = *reinterpret_cast<const f32x4*>(xp);
            rx1[s] = *reinterpret_cast<const f32x4*>(xp + FF);
        }
    };
    auto store_A = [&](char* Ab) {
        #pragma unroll
        for (int k = 0; k < KC; ++k) {
            bf16x8 w;
            #pragma unroll
            for (int e = 0; e < 4; ++e) {
                w[e]     = (__bf16)(rc0[k][e] * ra0[e]);
                w[e + 4] = (__bf16)(rc1[k][e] * ra1[e]);
            }
            *reinterpret_cast<bf16x8*>(Ab + (k * 64 + r_a) * 128 + ((g_a * 16) ^ swza_st)) = w;
        }
    };
    auto store_X = [&](char* Xb) {
        #pragma unroll
        for (int s = 0; s < 4; ++s) {
            const int c0 = tl_s[s] * 64 + f_s[s];
            const int coloff = (jj_s[s] * 2) ^ swzx_st[s];
            #pragma unroll
            for (int e = 0; e < 4; ++e) {
                union { __bf16 h[2]; unsigned u32; } pk;
                pk.h[0] = (__bf16)rx0[s][e];
                pk.h[1] = (__bf16)rx1[s][e];
                *reinterpret_cast<unsigned*>(Xb + (c0 + e) * 128 + coloff) = pk.u32;
            }
        }
    };
    f32x16 acc[KC][2] = {};
    const int xrow0 = (wm * 64 + l31) * 128;
    const int xrow1 = xrow0 + 32 * 128;
    const int arow  = (wn * 32 + l31) * 128;
    auto phase = [&](const char* AbR, const char* XbR, int kk) {
        const int off = ((kk * 2 + lg) ^ sw3) << 4;
        bf16x8 af0 = *reinterpret_cast<const bf16x8*>(XbR + xrow0 + off);
        bf16x8 af1 = *reinterpret_cast<const bf16x8*>(XbR + xrow1 + off);
        bf16x8 b0  = *reinterpret_cast<const bf16x8*>(AbR + arow + off);
        bf16x8 b1  = *reinterpret_cast<const bf16x8*>(AbR + 8192 + arow + off);
        bf16x8 b2  = *reinterpret_cast<const bf16x8*>(AbR + 16384 + arow + off);
        __builtin_amdgcn_s_setprio(1);
        acc[0][0] = MFMA_B(af0, b0, acc[0][0]); acc[0][1] = MFMA_B(af1, b0, acc[0][1]);
        acc[1][0] = MFMA_B(af0, b1, acc[1][0]); acc[1][1] = MFMA_B(af1, b1, acc[1][1]);
        acc[2][0] = MFMA_B(af0, b2, acc[2][0]); acc[2][1] = MFMA_B(af1, b2, acc[2][1]);
        __builtin_amdgcn_s_setprio(0);
    };
    load_tile(0);
    store_A(Ab0);
    store_X(Xb0);
    load_tile(64);
    asm volatile("s_waitcnt lgkmcnt(0)" ::: "memory");
    __builtin_amdgcn_s_barrier();
    for (int jt2 = 0; jt2 < 8; ++jt2) {
        const int jt = jt2 * 2;
        phase(Ab0, Xb0, 0);
        phase(Ab0, Xb0, 1);
        store_A(Ab1);
        phase(Ab0, Xb0, 2);
        store_X(Xb1);
        phase(Ab0, Xb0, 3);
        if (jt + 2 < 16) load_tile((jt + 2) * 64);
        asm volatile("s_waitcnt lgkmcnt(0)" ::: "memory");
        __builtin_amdgcn_s_barrier();
        phase(Ab1, Xb1, 0);
        phase(Ab1, Xb1, 1);
        if (jt + 1 < 15) store_A(Ab0);
        phase(Ab1, Xb1, 2);
        if (jt + 1 < 15) store_X(Xb0);
        phase(Ab1, Xb1, 3);
        if (jt + 3 < 16) load_tile((jt + 3) * 64);
        asm volatile("s_waitcnt lgkmcnt(0)" ::: "memory");
        __builtin_amdgcn_s_barrier();
    }
    {
        const int fi0 = wid * 3;
        #pragma unroll
        for (int q = 0; q < 3; ++q) {
            int fi = fi0 + q;
            int k  = fi >> 3;
            int mo = (fi >> 2) & 1;
            int s  = fi & 3;
            int o  = 32 * mo + l31;
            int fb = 32 * (s >> 1) + 16 * (s & 1) + 4 * lg;
            bf16x8 v;
            #pragma unroll
            for (int e = 0; e < 8; ++e) {
                int f = fb + (e & 3) + 8 * (e >> 2);
                v[e] = (__bf16)Theta[(k * FF + f) * FF + o];
            }
            *reinterpret_cast<bf16x8*>(lds_raw + (fi * 64 + lane) * 16) = v;
        }
    }
    __syncthreads();
    f32x16 of[2] = {};
    #pragma unroll
    for (int k = 0; k < KC; ++k) {
        #pragma unroll
        for (int s = 0; s < 4; ++s) {
            bf16x8 pb;
            #pragma unroll
            for (int e = 0; e < 8; ++e)
                pb[e] = (__bf16)acc[k][s >> 1][e + 8 * (s & 1)];
            #pragma unroll
            for (int mo = 0; mo < 2; ++mo) {
                bf16x8 th = *reinterpret_cast<const bf16x8*>(
                    lds_raw + ((((k * 2 + mo) * 4 + s) * 64) + lane) * 16);
                of[mo] = MFMA_B(pb, th, of[mo]);
            }
        }
    }
    const int t = t_base + wm;
    float* op = out + (((size_t)b * TT + t) * NN + i_base + wn * 32) * FF;
    #pragma unroll
    for (int mo = 0; mo < 2; ++mo) {
        #pragma unroll
        for (int r = 0; r < 16; ++r) {
            int row = (r & 3) + 8 * (r >> 2) + 4 * lg;
            int o   = 32 * mo + l31;
            float v = of[mo][r];
            op[(size_t)row * FF + o] = v > 0.0f ? v : 0.0f;
        }
    }
}

extern "C" void kernel_launch(void* const* d_in, const int* in_sizes, int n_in,
                              void* d_out, int out_size, void* d_ws, size_t ws_size,
                              hipStream_t stream) {
    const float* x     = (const float*)d_in[0];
    const float* att   = (const float*)d_in[1];
    const float* cheb  = (const float*)d_in[2];
    const float* Theta = (const float*)d_in[3];
    float* out = (float*)d_out;
    (void)in_sizes; (void)n_in; (void)out_size;

    if (ws_size >= YF_BYTES + CB_BYTES) {
        u16* yfr = (u16*)d_ws;
        u16* cbf = (u16*)((char*)d_ws + YF_BYTES);
        x_to_yfrags<<<dim3(BB * TT * 16), 256, 0, stream>>>(x, yfr);
        cheb_to_bf16<<<dim3(KC * NN * NN / (256 * 8)), 256, 0, stream>>>(cheb, cbf);
        cheb_main<<<dim3(BB * 16 * 6), 256, 0, stream>>>(yfr, att, cbf, Theta, out);
    } else {
        cheb_fused<<<dim3(BB * 16 * 3), 512, 0, stream>>>(x, att, cheb, Theta, out);
    }
}

// Round 9
// 105.944 us; speedup vs baseline: 1.1976x; 1.1976x over previous
//
#include <hip/hip_runtime.h>
#include <hip/hip_bf16.h>

// B=16, T=12, N=1024, F_IN=F_OUT=64, K=3
#define BB 16
#define TT 12
#define NN 1024
#define FF 64
#define KC 3

typedef __bf16  bf16x8 __attribute__((ext_vector_type(8)));
typedef float   f32x4  __attribute__((ext_vector_type(4)));
typedef float   f32x16 __attribute__((ext_vector_type(16)));
typedef unsigned short u16;

#define A_TILE 24576   // 3 * 64 * 128 B (one jt)
#define Y_TILE 32768   // 4 bt * 8192 B (one jt)
#define MFMA_B(a, b, c) __builtin_amdgcn_mfma_f32_32x32x16_bf16(a, b, c, 0, 0, 0)

// workspace: y_frags [192 bt][16 jt][512 chunk][8 e] bf16 = 25165824 B
//            cheb_bf [3][1024][1024] bf16 = 6291456 B
#define YF_BYTES 25165824ull
#define CB_BYTES 6291456ull

static __device__ __forceinline__ u16 f2bf(float v) {
    union { __bf16 b; u16 u; } c; c.b = (__bf16)v; return c.u;
}

static __device__ __forceinline__ void load_lds16(const void* g, void* l) {
    __builtin_amdgcn_global_load_lds(
        (const __attribute__((address_space(1))) unsigned int*)g,
        (__attribute__((address_space(3))) unsigned int*)l, 16, 0, 0);
}

// ---------------- prepass 1: x [B,T,N,F] f32 -> y_frags bf16 (proven) -------
__global__ __launch_bounds__(256) void x_to_yfrags(
    const float* __restrict__ x, u16* __restrict__ y)
{
    __shared__ char tl[64 * 128];
    const int tid = threadIdx.x;
    const int bt  = blockIdx.x >> 4;
    const int jt  = blockIdx.x & 15;
    const int f   = tid & 63;
    const int jr  = tid >> 6;

    const float* xp = x + ((size_t)bt * NN + jt * 64 + jr) * FF + f;
    #pragma unroll
    for (int stp = 0; stp < 16; ++stp) {
        int j = stp * 4 + jr;
        u16 h = f2bf(xp[stp * 4 * FF]);
        *reinterpret_cast<u16*>(tl + j * 128 + ((f * 2) ^ ((j & 7) << 4))) = h;
    }
    __syncthreads();

    u16* yo = y + ((size_t)bt * 16 + jt) * 4096;
    #pragma unroll
    for (int p = 0; p < 2; ++p) {
        int c  = tid + p * 256;
        int s  = c >> 6, fo = c & 63;
        int j0 = (s >> 1) * 16 + (s & 1) * 8;
        u16 h[8];
        #pragma unroll
        for (int e = 0; e < 8; ++e)
            h[e] = *reinterpret_cast<u16*>(tl + (j0 + e) * 128 + ((fo * 2) ^ (e << 4)));
        uint4 w;
        w.x = h[0] | ((unsigned)h[1] << 16);
        w.y = h[2] | ((unsigned)h[3] << 16);
        w.z = h[4] | ((unsigned)h[5] << 16);
        w.w = h[6] | ((unsigned)h[7] << 16);
        *reinterpret_cast<uint4*>(yo + (size_t)c * 8) = w;
    }
}

// ---------------- prepass 2: cheb f32 -> bf16 flat copy (proven) ------------
__global__ __launch_bounds__(256) void cheb_to_bf16(
    const float* __restrict__ c, u16* __restrict__ o)
{
    const size_t i = ((size_t)blockIdx.x * 256 + threadIdx.x) * 8;
    f32x4 a = *reinterpret_cast<const f32x4*>(c + i);
    f32x4 b = *reinterpret_cast<const f32x4*>(c + i + 4);
    u16 h[8];
    #pragma unroll
    for (int e = 0; e < 4; ++e) { h[e] = f2bf(a[e]); h[e + 4] = f2bf(b[e]); }
    uint4 w;
    w.x = h[0] | ((unsigned)h[1] << 16);
    w.y = h[2] | ((unsigned)h[3] << 16);
    w.z = h[4] | ((unsigned)h[5] << 16);
    w.w = h[6] | ((unsigned)h[7] << 16);
    *reinterpret_cast<uint4*>(o + i) = w;
}

// ---------------- main: 512 thr (8 waves), 768 blocks, y via LDS ------------
// block = (b, i-tile 64, t-quad); waves: wm = wid>>1 (t in quad), wn = wid&1
__global__ __launch_bounds__(512, 1) void cheb_main(
    const u16*  __restrict__ yfr,    // y_frags
    const float* __restrict__ att,   // [B,N,N] f32
    const u16*  __restrict__ chb,    // cheb bf16 [K,N,N]
    const float* __restrict__ Theta, // [K,F,F] f32
    float* __restrict__ out)         // [B,T,N,F] f32
{
    // [A0 | A1 | Y0 | Y1] = 24576*2 + 32768*2 = 114688 B
    __shared__ __align__(16) char lds[2 * A_TILE + 2 * Y_TILE];
    char* Ab0 = lds;
    char* Ab1 = lds + A_TILE;
    char* Yb0 = lds + 2 * A_TILE;
    char* Yb1 = Yb0 + Y_TILE;

    const int tid  = threadIdx.x;
    const int lane = tid & 63;
    const int wid  = tid >> 6;

    // XCD swizzle: 768 % 8 == 0, chunk 96
    const int wg = (blockIdx.x & 7) * 96 + (blockIdx.x >> 3);
    const int b  = wg / 48;
    const int it = (wg % 48) / 3;
    const int tc = wg % 3;
    const int i_base = it * 64;
    const int t_base = tc * 4;

    const int wm  = wid >> 1;   // 0..3 : t in quad
    const int wn  = wid & 1;    // 0..1 : i half
    const int l31 = lane & 31;
    const int lg  = lane >> 5;
    const int sw3 = (l31 >> 2) & 7;

    // A-staging map: r_a = tid>>3 (row), g_a = tid&7 (8-j group)
    const int r_a = tid >> 3;
    const int g_a = tid & 7;
    const int swza_st = ((r_a >> 2) & 7) << 4;
    const float* attR = att + ((size_t)b * NN + i_base + r_a) * NN + g_a * 8;
    const u16*   chR  = chb + ((size_t)(i_base + r_a)) * NN + g_a * 8;

    f32x16 acc[KC][2] = {};
    const int arow = (wn * 32 + l31) * 128;

    // staging registers for A inputs
    f32x4 ra0, ra1;
    bf16x8 rc[KC];

    auto LOADS = [&](int j0) {
        ra0 = *reinterpret_cast<const f32x4*>(attR + j0);
        ra1 = *reinterpret_cast<const f32x4*>(attR + j0 + 4);
        #pragma unroll
        for (int k = 0; k < KC; ++k)
            rc[k] = *reinterpret_cast<const bf16x8*>(chR + (size_t)k * NN * NN + j0);
    };
    auto FINISH = [&](char* Ab) {
        #pragma unroll
        for (int k = 0; k < KC; ++k) {
            bf16x8 w;
            #pragma unroll
            for (int e = 0; e < 4; ++e) {
                w[e]     = (__bf16)(ra0[e] * (float)rc[k][e]);
                w[e + 4] = (__bf16)(ra1[e] * (float)rc[k][e + 4]);
            }
            *reinterpret_cast<bf16x8*>(
                Ab + (k * 64 + r_a) * 128 + ((g_a * 16) ^ swza_st)) = w;
        }
    };

    // y tile staging: 4 bt tiles x 8192 B; wave w issues segments w*4..w*4+3,
    // each global_load_lds writes 64 lanes x 16 B = 1 KB (dest = uniform base + lane*16)
    auto loadY_lds = [&](char* Yb, int jt) {
        #pragma unroll
        for (int q = 0; q < 4; ++q) {
            int s    = wid * 4 + q;
            int tile = s >> 3;         // bt index 0..3
            int part = s & 7;          // 1KB part
            const u16* gp = yfr + ((size_t)(b * TT + t_base + tile) * 16 + jt) * 4096
                          + (size_t)(part * 64 + lane) * 8;
            load_lds16(gp, Yb + tile * 8192 + part * 1024);
        }
    };

    auto phase4 = [&](const char* Abase, const char* Ybase) {
        const char* yt = Ybase + wm * 8192;
        #pragma unroll
        for (int kk = 0; kk < 4; ++kk) {
            const int off  = ((kk * 2 + lg) ^ sw3) << 4;
            const int yoff = (kk * 2 + lg) * 1024 + l31 * 16;
            bf16x8 af0 = *reinterpret_cast<const bf16x8*>(yt + yoff);
            bf16x8 af1 = *reinterpret_cast<const bf16x8*>(yt + yoff + 512);
            bf16x8 b0 = *reinterpret_cast<const bf16x8*>(Abase + arow + off);
            bf16x8 b1 = *reinterpret_cast<const bf16x8*>(Abase + 8192 + arow + off);
            bf16x8 b2 = *reinterpret_cast<const bf16x8*>(Abase + 16384 + arow + off);
            __builtin_amdgcn_s_setprio(1);
            acc[0][0] = MFMA_B(af0, b0, acc[0][0]); acc[0][1] = MFMA_B(af1, b0, acc[0][1]);
            acc[1][0] = MFMA_B(af0, b1, acc[1][0]); acc[1][1] = MFMA_B(af1, b1, acc[1][1]);
            acc[2][0] = MFMA_B(af0, b2, acc[2][0]); acc[2][1] = MFMA_B(af1, b2, acc[2][1]);
            __builtin_amdgcn_s_setprio(0);
        }
    };

    // body(jt): issue y(jt+1)->altY; compute on (curA, curY); stage A(jt+1)->altA;
    // issue att/cheb(jt+2); counted vmcnt(5) drains y(jt+1) but leaves the 5
    // att/cheb loads in flight across the barrier.
    auto body = [&](char* curA, char* altA, char* curY, char* altY, int jt) {
        loadY_lds(altY, (jt + 1) & 15);
        __builtin_amdgcn_sched_barrier(0);    // pin issue order (y-lds before anything)
        phase4(curA, curY);
        if (jt < 15) {
            FINISH(altA);                     // compiler auto-waits att/cheb(jt+1)
            LOADS(((jt + 2) & 15) * 64);      // 5 loads issued
        }
        asm volatile("s_waitcnt vmcnt(5)" ::: "memory");
        asm volatile("s_waitcnt lgkmcnt(0)" ::: "memory");
        __builtin_amdgcn_s_barrier();
    };

    // prologue: y(0)+att/cheb(0) in flight; drain; stage A[0]; issue att/cheb(1)
    loadY_lds(Yb0, 0);
    LOADS(0);
    asm volatile("s_waitcnt vmcnt(0)" ::: "memory");
    FINISH(Ab0);
    LOADS(64);
    asm volatile("s_waitcnt lgkmcnt(0)" ::: "memory");
    __builtin_amdgcn_s_barrier();

    #pragma unroll 1
    for (int h = 0; h < 8; ++h) {
        body(Ab0, Ab1, Yb0, Yb1, 2 * h);
        body(Ab1, Ab0, Yb1, Yb0, 2 * h + 1);
    }

    // ---- stage Theta fragments into A0 region (24 frags * 64 lanes * 16B) ----
    {
        const int fi0 = wid * 3;
        #pragma unroll
        for (int q = 0; q < 3; ++q) {
            int fi = fi0 + q;
            int k  = fi >> 3;
            int mo = (fi >> 2) & 1;
            int s  = fi & 3;
            int o  = 32 * mo + l31;
            int fb = 32 * (s >> 1) + 16 * (s & 1) + 4 * lg;
            bf16x8 v;
            #pragma unroll
            for (int e = 0; e < 8; ++e) {
                int f = fb + (e & 3) + 8 * (e >> 2);
                v[e] = (__bf16)Theta[(k * FF + f) * FF + o];
            }
            *reinterpret_cast<bf16x8*>(lds + (fi * 64 + lane) * 16) = v;
        }
    }
    __syncthreads();

    // ---- epilogue: out[i][o] = sum_{k,f} rhsT[f][i]^T * Theta ----
    f32x16 of[2] = {};
    #pragma unroll
    for (int k = 0; k < KC; ++k) {
        #pragma unroll
        for (int s = 0; s < 4; ++s) {
            bf16x8 pb;
            #pragma unroll
            for (int e = 0; e < 8; ++e)
                pb[e] = (__bf16)acc[k][s >> 1][e + 8 * (s & 1)];
            #pragma unroll
            for (int mo = 0; mo < 2; ++mo) {
                bf16x8 th = *reinterpret_cast<const bf16x8*>(
                    lds + ((((k * 2 + mo) * 4 + s) * 64) + lane) * 16);
                of[mo] = MFMA_B(pb, th, of[mo]);
            }
        }
    }

    const int t = t_base + wm;
    float* op = out + (((size_t)b * TT + t) * NN + i_base + wn * 32) * FF;
    #pragma unroll
    for (int mo = 0; mo < 2; ++mo) {
        #pragma unroll
        for (int r = 0; r < 16; ++r) {
            int row = (r & 3) + 8 * (r >> 2) + 4 * lg;
            int o   = 32 * mo + l31;
            float v = of[mo][r];
            op[(size_t)row * FF + o] = v > 0.0f ? v : 0.0f;
        }
    }
}

// ---------------- fallback (R3 kernel, used when ws too small) ----------------
__global__ __launch_bounds__(512, 2) void cheb_fused(
    const float* __restrict__ x, const float* __restrict__ att,
    const float* __restrict__ cheb, const float* __restrict__ Theta,
    float* __restrict__ out)
{
    __shared__ __align__(16) char lds_raw[2 * (A_TILE + 32768)];
    char* Ab0 = lds_raw;
    char* Xb0 = lds_raw + A_TILE;
    char* Ab1 = lds_raw + A_TILE + 32768;
    char* Xb1 = Ab1 + A_TILE;

    const int tid  = threadIdx.x;
    const int lane = tid & 63;
    const int wid  = tid >> 6;
    const int wg = (blockIdx.x & 7) * 96 + (blockIdx.x >> 3);
    const int b  = wg / 48;
    const int it = (wg % 48) / 3;
    const int tc = wg % 3;
    const int i_base = it * 64;
    const int t_base = tc * 4;
    const int wm  = wid >> 1;
    const int wn  = wid & 1;
    const int l31 = lane & 31;
    const int lg  = lane >> 5;
    const int sw3 = (l31 >> 2) & 7;
    const float* attB = att + (size_t)b * NN * NN;
    const float* xB   = x + (size_t)b * TT * NN * FF;
    const int r_a = tid >> 3;
    const int g_a = tid & 7;
    const int swza_st = ((r_a >> 2) & 7) << 4;
    int tl_s[4], jj_s[4], f_s[4], swzx_st[4];
    #pragma unroll
    for (int s = 0; s < 4; ++s) {
        int u = tid + s * 512;
        tl_s[s] = u >> 9;
        int rem = u & 511;
        jj_s[s] = (rem >> 4) * 2;
        f_s[s]  = (rem & 15) * 4;
        swzx_st[s] = ((f_s[s] >> 2) & 7) << 4;
    }
    f32x4 ra0, ra1, rc0[KC], rc1[KC], rx0[4], rx1[4];
    auto load_tile = [&](int j0) {
        const float* ap = attB + (size_t)(i_base + r_a) * NN + j0 + g_a * 8;
        ra0 = *reinterpret_cast<const f32x4*>(ap);
        ra1 = *reinterpret_cast<const f32x4*>(ap + 4);
        #pragma unroll
        for (int k = 0; k < KC; ++k) {
            const float* cp = cheb + ((size_t)k * NN + i_base + r_a) * NN + j0 + g_a * 8;
            rc0[k] = *reinterpret_cast<const f32x4*>(cp);
            rc1[k] = *reinterpret_cast<const f32x4*>(cp + 4);
        }
        #pragma unroll
        for (int s = 0; s < 4; ++s) {
            const float* xp = xB + ((size_t)(t_base + tl_s[s]) * NN + j0 + jj_s[s]) * FF + f_s[s];
            rx0[s] = *reinterpret_cast<const f32x4*>(xp);
            rx1[s] = *reinterpret_cast<const f32x4*>(xp + FF);
        }
    };
    auto store_A = [&](char* Ab) {
        #pragma unroll
        for (int k = 0; k < KC; ++k) {
            bf16x8 w;
            #pragma unroll
            for (int e = 0; e < 4; ++e) {
                w[e]     = (__bf16)(rc0[k][e] * ra0[e]);
                w[e + 4] = (__bf16)(rc1[k][e] * ra1[e]);
            }
            *reinterpret_cast<bf16x8*>(Ab + (k * 64 + r_a) * 128 + ((g_a * 16) ^ swza_st)) = w;
        }
    };
    auto store_X = [&](char* Xb) {
        #pragma unroll
        for (int s = 0; s < 4; ++s) {
            const int c0 = tl_s[s] * 64 + f_s[s];
            const int coloff = (jj_s[s] * 2) ^ swzx_st[s];
            #pragma unroll
            for (int e = 0; e < 4; ++e) {
                union { __bf16 h[2]; unsigned u32; } pk;
                pk.h[0] = (__bf16)rx0[s][e];
                pk.h[1] = (__bf16)rx1[s][e];
                *reinterpret_cast<unsigned*>(Xb + (c0 + e) * 128 + coloff) = pk.u32;
            }
        }
    };
    f32x16 acc[KC][2] = {};
    const int xrow0 = (wm * 64 + l31) * 128;
    const int xrow1 = xrow0 + 32 * 128;
    const int arow  = (wn * 32 + l31) * 128;
    auto phase = [&](const char* AbR, const char* XbR, int kk) {
        const int off = ((kk * 2 + lg) ^ sw3) << 4;
        bf16x8 af0 = *reinterpret_cast<const bf16x8*>(XbR + xrow0 + off);
        bf16x8 af1 = *reinterpret_cast<const bf16x8*>(XbR + xrow1 + off);
        bf16x8 b0  = *reinterpret_cast<const bf16x8*>(AbR + arow + off);
        bf16x8 b1  = *reinterpret_cast<const bf16x8*>(AbR + 8192 + arow + off);
        bf16x8 b2  = *reinterpret_cast<const bf16x8*>(AbR + 16384 + arow + off);
        __builtin_amdgcn_s_setprio(1);
        acc[0][0] = MFMA_B(af0, b0, acc[0][0]); acc[0][1] = MFMA_B(af1, b0, acc[0][1]);
        acc[1][0] = MFMA_B(af0, b1, acc[1][0]); acc[1][1] = MFMA_B(af1, b1, acc[1][1]);
        acc[2][0] = MFMA_B(af0, b2, acc[2][0]); acc[2][1] = MFMA_B(af1, b2, acc[2][1]);
        __builtin_amdgcn_s_setprio(0);
    };
    load_tile(0);
    store_A(Ab0);
    store_X(Xb0);
    load_tile(64);
    asm volatile("s_waitcnt lgkmcnt(0)" ::: "memory");
    __builtin_amdgcn_s_barrier();
    for (int jt2 = 0; jt2 < 8; ++jt2) {
        const int jt = jt2 * 2;
        phase(Ab0, Xb0, 0);
        phase(Ab0, Xb0, 1);
        store_A(Ab1);
        phase(Ab0, Xb0, 2);
        store_X(Xb1);
        phase(Ab0, Xb0, 3);
        if (jt + 2 < 16) load_tile((jt + 2) * 64);
        asm volatile("s_waitcnt lgkmcnt(0)" ::: "memory");
        __builtin_amdgcn_s_barrier();
        phase(Ab1, Xb1, 0);
        phase(Ab1, Xb1, 1);
        if (jt + 1 < 15) store_A(Ab0);
        phase(Ab1, Xb1, 2);
        if (jt + 1 < 15) store_X(Xb0);
        phase(Ab1, Xb1, 3);
        if (jt + 3 < 16) load_tile((jt + 3) * 64);
        asm volatile("s_waitcnt lgkmcnt(0)" ::: "memory");
        __builtin_amdgcn_s_barrier();
    }
    {
        const int fi0 = wid * 3;
        #pragma unroll
        for (int q = 0; q < 3; ++q) {
            int fi = fi0 + q;
            int k  = fi >> 3;
            int mo = (fi >> 2) & 1;
            int s  = fi & 3;
            int o  = 32 * mo + l31;
            int fb = 32 * (s >> 1) + 16 * (s & 1) + 4 * lg;
            bf16x8 v;
            #pragma unroll
            for (int e = 0; e < 8; ++e) {
                int f = fb + (e & 3) + 8 * (e >> 2);
                v[e] = (__bf16)Theta[(k * FF + f) * FF + o];
            }
            *reinterpret_cast<bf16x8*>(lds_raw + (fi * 64 + lane) * 16) = v;
        }
    }
    __syncthreads();
    f32x16 of[2] = {};
    #pragma unroll
    for (int k = 0; k < KC; ++k) {
        #pragma unroll
        for (int s = 0; s < 4; ++s) {
            bf16x8 pb;
            #pragma unroll
            for (int e = 0; e < 8; ++e)
                pb[e] = (__bf16)acc[k][s >> 1][e + 8 * (s & 1)];
            #pragma unroll
            for (int mo = 0; mo < 2; ++mo) {
                bf16x8 th = *reinterpret_cast<const bf16x8*>(
                    lds_raw + ((((k * 2 + mo) * 4 + s) * 64) + lane) * 16);
                of[mo] = MFMA_B(pb, th, of[mo]);
            }
        }
    }
    const int t = t_base + wm;
    float* op = out + (((size_t)b * TT + t) * NN + i_base + wn * 32) * FF;
    #pragma unroll
    for (int mo = 0; mo < 2; ++mo) {
        #pragma unroll
        for (int r = 0; r < 16; ++r) {
            int row = (r & 3) + 8 * (r >> 2) + 4 * lg;
            int o   = 32 * mo + l31;
            float v = of[mo][r];
            op[(size_t)row * FF + o] = v > 0.0f ? v : 0.0f;
        }
    }
}

extern "C" void kernel_launch(void* const* d_in, const int* in_sizes, int n_in,
                              void* d_out, int out_size, void* d_ws, size_t ws_size,
                              hipStream_t stream) {
    const float* x     = (const float*)d_in[0];
    const float* att   = (const float*)d_in[1];
    const float* cheb  = (const float*)d_in[2];
    const float* Theta = (const float*)d_in[3];
    float* out = (float*)d_out;
    (void)in_sizes; (void)n_in; (void)out_size;

    if (ws_size >= YF_BYTES + CB_BYTES) {
        u16* yfr = (u16*)d_ws;
        u16* cbf = (u16*)((char*)d_ws + YF_BYTES);
        x_to_yfrags<<<dim3(BB * TT * 16), 256, 0, stream>>>(x, yfr);
        cheb_to_bf16<<<dim3(KC * NN * NN / (256 * 8)), 256, 0, stream>>>(cheb, cbf);
        cheb_main<<<dim3(BB * 16 * 3), 512, 0, stream>>>(yfr, att, cbf, Theta, out);
    } else {
        cheb_fused<<<dim3(BB * 16 * 3), 512, 0, stream>>>(x, att, cheb, Theta, out);
    }
}